// Round 1
// baseline (1523.847 us; speedup 1.0000x reference)
//
#include <hip/hip_runtime.h>
#include <hip/hip_bf16.h>
#include <cstddef>

// Problem constants
#define B_  4
#define T_  4096
#define D_  1024
#define H_  16
#define DH_ 64
#define R_  256
#define BT_ (B_ * T_)       // 16384
#define TWO_D_ (2 * D_)     // 2048

// elu(x)+1 : x>0 ? x+1 : exp(x)
__device__ __forceinline__ float elu1(float x) {
    return x > 0.0f ? x + 1.0f : __expf(x);
}

// ---------------------------------------------------------------------------
// Generic fp32 tiled GEMM: C[M,N] = A[M,K] @ B[K,N] + bias[N], epilogue EPI.
// EPI 0: none; 1: elu1 on all; 2: elu1 where (col & 127) < 64  (k-part of kv)
// Tiles: 128x128x8, 256 threads, 8x8 accumulators per thread.
// Assumes M%128==0, N%128==0, K%8==0 (true for all our shapes).
// ---------------------------------------------------------------------------
#define TM 128
#define TN 128
#define TK 8

template <int EPI>
__global__ __launch_bounds__(256) void gemm_f32(
    const float* __restrict__ A, const float* __restrict__ Bm,
    const float* __restrict__ bias, float* __restrict__ C,
    int M, int N, int K)
{
    __shared__ float As[TK][TM];   // transposed A tile
    __shared__ float Bs[TK][TN];

    const int tid = threadIdx.x;
    const int bm = blockIdx.y * TM;
    const int bn = blockIdx.x * TN;
    const int tx = tid & 15;       // 0..15
    const int ty = tid >> 4;       // 0..15

    // Load assignments
    const int arow  = tid >> 1;        // 0..127
    const int acol4 = (tid & 1) * 4;   // 0 or 4
    const int brow  = tid >> 5;        // 0..7
    const int bcol4 = (tid & 31) * 4;  // 0..124

    float acc[8][8];
#pragma unroll
    for (int i = 0; i < 8; ++i)
#pragma unroll
        for (int j = 0; j < 8; ++j) acc[i][j] = 0.0f;

    for (int k0 = 0; k0 < K; k0 += TK) {
        float4 av = *(const float4*)(A + (size_t)(bm + arow) * K + k0 + acol4);
        float4 bv = *(const float4*)(Bm + (size_t)(k0 + brow) * N + bn + bcol4);
        __syncthreads();
        As[acol4 + 0][arow] = av.x;
        As[acol4 + 1][arow] = av.y;
        As[acol4 + 2][arow] = av.z;
        As[acol4 + 3][arow] = av.w;
        *(float4*)(&Bs[brow][bcol4]) = bv;
        __syncthreads();
#pragma unroll
        for (int k = 0; k < TK; ++k) {
            float a[8], b[8];
            *(float4*)(a)     = *(const float4*)(&As[k][ty * 8]);
            *(float4*)(a + 4) = *(const float4*)(&As[k][ty * 8 + 4]);
            *(float4*)(b)     = *(const float4*)(&Bs[k][tx * 8]);
            *(float4*)(b + 4) = *(const float4*)(&Bs[k][tx * 8 + 4]);
#pragma unroll
            for (int i = 0; i < 8; ++i)
#pragma unroll
                for (int j = 0; j < 8; ++j) acc[i][j] += a[i] * b[j];
        }
    }

    // Epilogue + store (two float4 per row)
#pragma unroll
    for (int i = 0; i < 8; ++i) {
        const int row = bm + ty * 8 + i;
        float v[8];
#pragma unroll
        for (int j = 0; j < 8; ++j) {
            const int col = bn + tx * 8 + j;
            float x = acc[i][j] + bias[col];
            if (EPI == 1) x = elu1(x);
            else if (EPI == 2) { if ((col & 127) < 64) x = elu1(x); }
            v[j] = x;
        }
        float* dst = C + (size_t)row * N + bn + tx * 8;
        *(float4*)(dst)     = *(float4*)(v);
        *(float4*)(dst + 4) = *(float4*)(v + 4);
    }
}

// ---------------------------------------------------------------------------
// context[b,h,d,e] = sum_t k[b,t,h,d] * v[b,t,h,e];  ksum[b,h,d] = sum_t k.
// kv layout: kv[b][t][h*128 + j], j<64 -> k (already elu1'd), j>=64 -> v.
// Grid: (B*H) * (T/TCHUNK) blocks, 256 threads. Atomic accumulate into ctx.
// ---------------------------------------------------------------------------
#define TCHUNK 512
#define TTILE  16

__global__ __launch_bounds__(256) void ctx_kernel(
    const float* __restrict__ kv, float* __restrict__ ctx,
    float* __restrict__ ksum)
{
    const int nchunk = T_ / TCHUNK;            // 8
    const int bh = blockIdx.x / nchunk;        // 0..63
    const int chunk = blockIdx.x % nchunk;
    const int b = bh / H_;
    const int h = bh % H_;
    const int tid = threadIdx.x;
    const int d  = tid >> 2;                   // 0..63
    const int e0 = (tid & 3) << 4;             // 0,16,32,48

    __shared__ float sh[TTILE * 128];

    float acc[16];
#pragma unroll
    for (int j = 0; j < 16; ++j) acc[j] = 0.0f;
    float ks = 0.0f;

    const float* base = kv + ((size_t)b * T_ + (size_t)chunk * TCHUNK) * TWO_D_ + h * 128;
    const int ltok = tid >> 4;        // 0..15
    const int lj   = (tid & 15) * 8;  // 0..120

    for (int t0 = 0; t0 < TCHUNK; t0 += TTILE) {
        const float* src = base + (size_t)(t0 + ltok) * TWO_D_ + lj;
        float4 v0 = *(const float4*)(src);
        float4 v1 = *(const float4*)(src + 4);
        __syncthreads();
        *(float4*)(sh + ltok * 128 + lj)     = v0;
        *(float4*)(sh + ltok * 128 + lj + 4) = v1;
        __syncthreads();
#pragma unroll
        for (int tt = 0; tt < TTILE; ++tt) {
            const float kd = sh[tt * 128 + d];
            ks += kd;
            float vv[16];
            *(float4*)(vv)      = *(const float4*)(sh + tt * 128 + 64 + e0);
            *(float4*)(vv + 4)  = *(const float4*)(sh + tt * 128 + 64 + e0 + 4);
            *(float4*)(vv + 8)  = *(const float4*)(sh + tt * 128 + 64 + e0 + 8);
            *(float4*)(vv + 12) = *(const float4*)(sh + tt * 128 + 64 + e0 + 12);
#pragma unroll
            for (int j = 0; j < 16; ++j) acc[j] += kd * vv[j];
        }
    }

    float* cdst = ctx + (size_t)bh * 4096 + d * 64 + e0;
#pragma unroll
    for (int j = 0; j < 16; ++j) atomicAdd(cdst + j, acc[j]);
    if ((tid & 3) == 0) atomicAdd(ksum + bh * 64 + d, ks);
}

// ---------------------------------------------------------------------------
// out[b,t,h,e] = z * sum_d q[b,t,h,d] * ctx[b,h,d,e],
// z = 1/(sum_d q[b,t,h,d]*ksum[b,h,d] + 1e-6).
// Grid: B*H*(T/64) blocks, 256 threads; block handles 64 tokens of one (b,h).
// ---------------------------------------------------------------------------
__global__ __launch_bounds__(256) void out_kernel(
    const float* __restrict__ q, const float* __restrict__ ctx,
    const float* __restrict__ ksum, float* __restrict__ outb)
{
    const int ntile = T_ / 64;                 // 64
    const int bh = blockIdx.x / ntile;
    const int tt0 = (blockIdx.x % ntile) * 64;
    const int b = bh / H_;
    const int h = bh % H_;
    const int tid = threadIdx.x;

    __shared__ float cs[4096];
    __shared__ float qs[4096];
    __shared__ float ks[64];
    __shared__ float zs[64];

    // load ctx tile (64x64)
    {
        const float4* src = (const float4*)(ctx + (size_t)bh * 4096);
        float4* dst = (float4*)cs;
#pragma unroll
        for (int r = 0; r < 4; ++r) dst[tid + r * 256] = src[tid + r * 256];
    }
    // load ksum
    if (tid < 16) ((float4*)ks)[tid] = ((const float4*)(ksum + bh * 64))[tid];
    // load q tile: 64 tokens x 64 dims
    {
        const float* qbase = q + ((size_t)b * T_ + tt0) * D_ + h * DH_;
#pragma unroll
        for (int r = 0; r < 4; ++r) {
            int g = tid + r * 256;             // float4 index 0..1023
            int tt = g >> 4;
            int dd4 = g & 15;
            ((float4*)qs)[g] = *(const float4*)(qbase + (size_t)tt * D_ + dd4 * 4);
        }
    }
    __syncthreads();

    // z per token
    if (tid < 64) {
        float s = 0.0f;
#pragma unroll
        for (int dd = 0; dd < 64; ++dd) s += qs[tid * 64 + dd] * ks[dd];
        zs[tid] = 1.0f / (s + 1e-6f);
    }
    __syncthreads();

    // matvec: thread owns token tt = tid>>2, cols e0..e0+15
    const int tt = tid >> 2;
    const int e0 = (tid & 3) << 4;
    float acc[16];
#pragma unroll
    for (int j = 0; j < 16; ++j) acc[j] = 0.0f;
#pragma unroll 8
    for (int dd = 0; dd < 64; ++dd) {
        const float qv = qs[tt * 64 + dd];
        float cv[16];
        *(float4*)(cv)      = *(const float4*)(cs + dd * 64 + e0);
        *(float4*)(cv + 4)  = *(const float4*)(cs + dd * 64 + e0 + 4);
        *(float4*)(cv + 8)  = *(const float4*)(cs + dd * 64 + e0 + 8);
        *(float4*)(cv + 12) = *(const float4*)(cs + dd * 64 + e0 + 12);
#pragma unroll
        for (int j = 0; j < 16; ++j) acc[j] += qv * cv[j];
    }
    const float z = zs[tt];
    float* dst = outb + ((size_t)b * T_ + tt0 + tt) * D_ + h * DH_ + e0;
    float v[16];
#pragma unroll
    for (int j = 0; j < 16; ++j) v[j] = acc[j] * z;
    *(float4*)(dst)      = *(float4*)(v);
    *(float4*)(dst + 4)  = *(float4*)(v + 4);
    *(float4*)(dst + 8)  = *(float4*)(v + 8);
    *(float4*)(dst + 12) = *(float4*)(v + 12);
}

// ---------------------------------------------------------------------------
extern "C" void kernel_launch(void* const* d_in, const int* in_sizes, int n_in,
                              void* d_out, int out_size, void* d_ws, size_t ws_size,
                              hipStream_t stream) {
    const float* x  = (const float*)d_in[0];
    const float* Wq = (const float*)d_in[1];
    const float* bq = (const float*)d_in[2];
    const float* Wd = (const float*)d_in[3];
    const float* bd = (const float*)d_in[4];
    const float* Wu = (const float*)d_in[5];
    const float* bu = (const float*)d_in[6];
    const float* Wo = (const float*)d_in[7];
    const float* bo = (const float*)d_in[8];
    float* out = (float*)d_out;

    // Workspace layout (floats)
    float* q    = (float*)d_ws;                         // BT*D      = 16.7M
    float* xd   = q + (size_t)BT_ * D_;                 // BT*R      = 4.2M
    float* kv   = xd + (size_t)BT_ * R_;                // BT*2D     = 33.6M
    float* ctx  = kv + (size_t)BT_ * TWO_D_;            // 64*4096
    float* ksum = ctx + (size_t)B_ * H_ * DH_ * DH_;    // 64*64
    float* outb = kv;  // alias: kv no longer needed after ctx_kernel

    // zero the atomic accumulators (re-poisoned to 0xAA before every call)
    hipMemsetAsync(ctx, 0, (size_t)(B_ * H_ * DH_ * DH_ + B_ * H_ * DH_) * sizeof(float), stream);

    // 1) q = elu1(x @ Wq + bq)
    gemm_f32<1><<<dim3(D_ / TN, BT_ / TM), 256, 0, stream>>>(x, Wq, bq, q, BT_, D_, D_);
    // 2) xd = x @ Wd + bd
    gemm_f32<0><<<dim3(R_ / TN, BT_ / TM), 256, 0, stream>>>(x, Wd, bd, xd, BT_, R_, D_);
    // 3) kv = xd @ Wu + bu, elu1 on k-part ((col&127)<64)
    gemm_f32<2><<<dim3(TWO_D_ / TN, BT_ / TM), 256, 0, stream>>>(xd, Wu, bu, kv, BT_, TWO_D_, R_);
    // 4) context + ksum
    ctx_kernel<<<B_ * H_ * (T_ / TCHUNK), 256, 0, stream>>>(kv, ctx, ksum);
    // 5) out = z * (q @ ctx)
    out_kernel<<<B_ * H_ * (T_ / 64), 256, 0, stream>>>(q, ctx, ksum, outb);
    // 6) final = outb @ Wo + bo
    gemm_f32<0><<<dim3(D_ / TN, BT_ / TM), 256, 0, stream>>>(outb, Wo, bo, out, BT_, D_, D_);
}

// Round 2
// 551.272 us; speedup vs baseline: 2.7642x; 2.7642x over previous
//
#include <hip/hip_runtime.h>
#include <hip/hip_bf16.h>
#include <cstddef>
#include <cstdint>

// Problem constants
#define B_  4
#define T_  4096
#define D_  1024
#define H_  16
#define DH_ 64
#define R_  256
#define BT_ (B_ * T_)       // 16384
#define TWO_D_ (2 * D_)     // 2048

typedef __attribute__((ext_vector_type(8))) short short8;
typedef __attribute__((ext_vector_type(4))) float f32x4;

__device__ __forceinline__ float elu1(float x) {
    return x > 0.0f ? x + 1.0f : __expf(x);
}

__device__ __forceinline__ float bf2f(short u) {
    union { uint32_t i; float f; } c;
    c.i = ((uint32_t)(uint16_t)u) << 16;
    return c.f;
}

// async global->LDS, 16B per lane. LDS dest semantics: wave-uniform base +
// lane*16 (lane0's pointer is used); our per-lane pointers match that layout.
typedef __attribute__((address_space(1))) void void_g;
typedef __attribute__((address_space(3))) void void_l;
__device__ __forceinline__ void gld_lds16(const void* g, void* l) {
    __builtin_amdgcn_global_load_lds(
        (const void_g*)(uintptr_t)g,
        (void_l*)(uint32_t)(uintptr_t)l,
        16, 0, 0);
}

// ---------------------------------------------------------------------------
// bf16 MFMA GEMM (m97 structure): C[M,N] = A[M,K] @ Bt[N,K]^T + bias.
// 128x128x32 tiles, 256 threads = 4 waves in 2x2, each wave 4x4 of 16x16x32.
// EPI 0: none; 1: elu1 all; 2: elu1 where (col&127)<64 (k-part of kv).
// OT: float or __hip_bfloat16 output.
// Requires M%128==0, N%128==0, K%32==0.
// ---------------------------------------------------------------------------
#define BM 128
#define BN 128
#define BK 32

__device__ __forceinline__ void store_out(float* p, float v) { *p = v; }
__device__ __forceinline__ void store_out(__hip_bfloat16* p, float v) { *p = __float2bfloat16(v); }

template<int EPI, typename OT>
__global__ __launch_bounds__(256) void gemm_bf16(
    const __hip_bfloat16* __restrict__ A,
    const __hip_bfloat16* __restrict__ Bt,
    const float* __restrict__ bias,
    OT* __restrict__ C,
    int M, int N, int K)
{
    __shared__ alignas(16) __hip_bfloat16 As[BM * BK];  // [128][32], 8 KB
    __shared__ alignas(16) __hip_bfloat16 Bs[BN * BK];  // [128][32] (B^T tile)

    const int tid  = threadIdx.x;
    const int lane = tid & 63;
    const int wm   = (tid >> 7) * 64;         // wave row offset (0/64)
    const int wn   = ((tid >> 6) & 1) * 64;   // wave col offset (0/64)
    const int bm   = blockIdx.y * BM;
    const int bn   = blockIdx.x * BN;
    const int r15  = lane & 15;
    const int kg   = lane >> 4;               // 0..3

    f32x4 acc[4][4] = {};

    // staging: chunk c (16 B) -> LDS offset c*16; global row c>>2, col8 (c&3)*8
    const int c0 = tid, c1 = tid + 256;
    const __hip_bfloat16* a0 = A  + (size_t)(bm + (c0 >> 2)) * K + (c0 & 3) * 8;
    const __hip_bfloat16* a1 = A  + (size_t)(bm + (c1 >> 2)) * K + (c1 & 3) * 8;
    const __hip_bfloat16* b0 = Bt + (size_t)(bn + (c0 >> 2)) * K + (c0 & 3) * 8;
    const __hip_bfloat16* b1 = Bt + (size_t)(bn + (c1 >> 2)) * K + (c1 & 3) * 8;

    for (int k0 = 0; k0 < K; k0 += BK) {
        gld_lds16(a0 + k0, As + c0 * 8);
        gld_lds16(a1 + k0, As + c1 * 8);
        gld_lds16(b0 + k0, Bs + c0 * 8);
        gld_lds16(b1 + k0, Bs + c1 * 8);
        __syncthreads();   // drains vmcnt(0): staged data visible

        short8 af[4], bf[4];
#pragma unroll
        for (int i = 0; i < 4; ++i) {
            af[i] = *(const short8*)(As + (wm + i * 16 + r15) * BK + kg * 8);
            bf[i] = *(const short8*)(Bs + (wn + i * 16 + r15) * BK + kg * 8);
        }
#pragma unroll
        for (int i = 0; i < 4; ++i)
#pragma unroll
            for (int j = 0; j < 4; ++j)
                acc[i][j] = __builtin_amdgcn_mfma_f32_16x16x32_bf16(af[i], bf[j], acc[i][j], 0, 0, 0);
        __syncthreads();   // protect LDS before next stage
    }

    // epilogue: C/D layout col=lane&15, row=(lane>>4)*4+reg  [m89-verified]
    const int row0 = bm + wm + (lane >> 4) * 4;
#pragma unroll
    for (int j = 0; j < 4; ++j) {
        const int col = bn + wn + j * 16 + r15;
        const float bv = bias[col];
        const bool k_part = (EPI == 2) && ((col & 64) == 0); // (col&127)<64
#pragma unroll
        for (int i = 0; i < 4; ++i) {
#pragma unroll
            for (int r = 0; r < 4; ++r) {
                float v = acc[i][j][r] + bv;
                if (EPI == 1) v = elu1(v);
                else if (EPI == 2) { if (k_part) v = elu1(v); }
                store_out(C + (size_t)(row0 + i * 16 + r) * N + col, v);
            }
        }
    }
}

// ---------------------------------------------------------------------------
// fp32 -> bf16 flat cast, 8 elems/thread
// ---------------------------------------------------------------------------
__global__ __launch_bounds__(256) void cast_bf16_kernel(
    const float* __restrict__ s, __hip_bfloat16* __restrict__ d, int n)
{
    const int i = (blockIdx.x * 256 + threadIdx.x) * 8;
    if (i >= n) return;
    float4 v0 = *(const float4*)(s + i);
    float4 v1 = *(const float4*)(s + i + 4);
    __hip_bfloat16 t[8];
    t[0] = __float2bfloat16(v0.x); t[1] = __float2bfloat16(v0.y);
    t[2] = __float2bfloat16(v0.z); t[3] = __float2bfloat16(v0.w);
    t[4] = __float2bfloat16(v1.x); t[5] = __float2bfloat16(v1.y);
    t[6] = __float2bfloat16(v1.z); t[7] = __float2bfloat16(v1.w);
    *(short8*)(d + i) = *(const short8*)t;
}

// ---------------------------------------------------------------------------
// Wt[n][k] = bf16(W[k][n]).  W is [K][N], grid (N/32, K/32), 256 threads.
// ---------------------------------------------------------------------------
__global__ __launch_bounds__(256) void transpose_cast(
    const float* __restrict__ W, __hip_bfloat16* __restrict__ Wt, int K, int N)
{
    __shared__ float t[32][33];
    const int n0 = blockIdx.x * 32, k0 = blockIdx.y * 32;
    const int c = threadIdx.x & 31, r = threadIdx.x >> 5;   // r 0..7
#pragma unroll
    for (int rr = r; rr < 32; rr += 8)
        t[rr][c] = W[(size_t)(k0 + rr) * N + n0 + c];
    __syncthreads();
#pragma unroll
    for (int rr = r; rr < 32; rr += 8)
        Wt[(size_t)(n0 + rr) * K + k0 + c] = __float2bfloat16(t[c][rr]);
}

// ---------------------------------------------------------------------------
// context[b,h,d,e] = sum_t k * v;  ksum[b,h,d] = sum_t k.   kv is bf16.
// ---------------------------------------------------------------------------
#define TCHUNK 512
#define TTILE  16

__global__ __launch_bounds__(256) void ctx_kernel(
    const __hip_bfloat16* __restrict__ kv, float* __restrict__ ctx,
    float* __restrict__ ksum)
{
    const int nchunk = T_ / TCHUNK;            // 8
    const int bh = blockIdx.x / nchunk;        // 0..63
    const int chunk = blockIdx.x % nchunk;
    const int b = bh / H_;
    const int h = bh % H_;
    const int tid = threadIdx.x;
    const int d  = tid >> 2;                   // 0..63
    const int e0 = (tid & 3) << 4;             // 0,16,32,48

    __shared__ float sh[TTILE * 128];

    float acc[16];
#pragma unroll
    for (int j = 0; j < 16; ++j) acc[j] = 0.0f;
    float ks = 0.0f;

    const __hip_bfloat16* base =
        kv + ((size_t)b * T_ + (size_t)chunk * TCHUNK) * TWO_D_ + h * 128;
    const int ltok = tid >> 4;        // 0..15
    const int lj   = (tid & 15) * 8;  // 0..120

    for (int t0 = 0; t0 < TCHUNK; t0 += TTILE) {
        short8 raw = *(const short8*)(base + (size_t)(t0 + ltok) * TWO_D_ + lj);
        __syncthreads();
#pragma unroll
        for (int u = 0; u < 8; ++u) sh[ltok * 128 + lj + u] = bf2f(raw[u]);
        __syncthreads();
#pragma unroll
        for (int tt = 0; tt < TTILE; ++tt) {
            const float kd = sh[tt * 128 + d];
            ks += kd;
            float vv[16];
            *(float4*)(vv)      = *(const float4*)(sh + tt * 128 + 64 + e0);
            *(float4*)(vv + 4)  = *(const float4*)(sh + tt * 128 + 64 + e0 + 4);
            *(float4*)(vv + 8)  = *(const float4*)(sh + tt * 128 + 64 + e0 + 8);
            *(float4*)(vv + 12) = *(const float4*)(sh + tt * 128 + 64 + e0 + 12);
#pragma unroll
            for (int j = 0; j < 16; ++j) acc[j] += kd * vv[j];
        }
    }

    float* cdst = ctx + (size_t)bh * 4096 + d * 64 + e0;
#pragma unroll
    for (int j = 0; j < 16; ++j) atomicAdd(cdst + j, acc[j]);
    if ((tid & 3) == 0) atomicAdd(ksum + bh * 64 + d, ks);
}

// ---------------------------------------------------------------------------
// out[b,t,h,e] = z * sum_d q*ctx,  z = 1/(q . ksum + 1e-6).  Output bf16.
// ---------------------------------------------------------------------------
__global__ __launch_bounds__(256) void out_kernel(
    const float* __restrict__ q, const float* __restrict__ ctx,
    const float* __restrict__ ksum, __hip_bfloat16* __restrict__ outb)
{
    const int ntile = T_ / 64;                 // 64
    const int bh = blockIdx.x / ntile;
    const int tt0 = (blockIdx.x % ntile) * 64;
    const int b = bh / H_;
    const int h = bh % H_;
    const int tid = threadIdx.x;

    __shared__ float cs[4096];
    __shared__ float qs[4096];
    __shared__ float ks[64];
    __shared__ float zs[64];

    {
        const float4* src = (const float4*)(ctx + (size_t)bh * 4096);
        float4* dst = (float4*)cs;
#pragma unroll
        for (int r = 0; r < 4; ++r) dst[tid + r * 256] = src[tid + r * 256];
    }
    if (tid < 16) ((float4*)ks)[tid] = ((const float4*)(ksum + bh * 64))[tid];
    {
        const float* qbase = q + ((size_t)b * T_ + tt0) * D_ + h * DH_;
#pragma unroll
        for (int r = 0; r < 4; ++r) {
            int g = tid + r * 256;
            int tt = g >> 4;
            int dd4 = g & 15;
            ((float4*)qs)[g] = *(const float4*)(qbase + (size_t)tt * D_ + dd4 * 4);
        }
    }
    __syncthreads();

    if (tid < 64) {
        float s = 0.0f;
#pragma unroll
        for (int dd = 0; dd < 64; ++dd) s += qs[tid * 64 + dd] * ks[dd];
        zs[tid] = 1.0f / (s + 1e-6f);
    }
    __syncthreads();

    const int tt = tid >> 2;
    const int e0 = (tid & 3) << 4;
    float acc[16];
#pragma unroll
    for (int j = 0; j < 16; ++j) acc[j] = 0.0f;
#pragma unroll 8
    for (int dd = 0; dd < 64; ++dd) {
        const float qv = qs[tt * 64 + dd];
        float cv[16];
        *(float4*)(cv)      = *(const float4*)(cs + dd * 64 + e0);
        *(float4*)(cv + 4)  = *(const float4*)(cs + dd * 64 + e0 + 4);
        *(float4*)(cv + 8)  = *(const float4*)(cs + dd * 64 + e0 + 8);
        *(float4*)(cv + 12) = *(const float4*)(cs + dd * 64 + e0 + 12);
#pragma unroll
        for (int j = 0; j < 16; ++j) acc[j] += qv * cv[j];
    }
    const float z = zs[tt];
    __hip_bfloat16 tb[16];
#pragma unroll
    for (int j = 0; j < 16; ++j) tb[j] = __float2bfloat16(acc[j] * z);
    __hip_bfloat16* dst = outb + ((size_t)b * T_ + tt0 + tt) * D_ + h * DH_ + e0;
    *(short8*)(dst)     = *(const short8*)(tb);
    *(short8*)(dst + 8) = *(const short8*)(tb + 8);
}

// ---------------------------------------------------------------------------
extern "C" void kernel_launch(void* const* d_in, const int* in_sizes, int n_in,
                              void* d_out, int out_size, void* d_ws, size_t ws_size,
                              hipStream_t stream) {
    const float* x  = (const float*)d_in[0];
    const float* Wq = (const float*)d_in[1];
    const float* bq = (const float*)d_in[2];
    const float* Wd = (const float*)d_in[3];
    const float* bd = (const float*)d_in[4];
    const float* Wu = (const float*)d_in[5];
    const float* bu = (const float*)d_in[6];
    const float* Wo = (const float*)d_in[7];
    const float* bo = (const float*)d_in[8];
    float* out = (float*)d_out;

    // Workspace layout (~183 MB total; round-1 used 219 MB OK)
    __hip_bfloat16* xb  = (__hip_bfloat16*)d_ws;          // BT*D
    __hip_bfloat16* WqT = xb  + (size_t)BT_ * D_;         // [D][D]
    __hip_bfloat16* WdT = WqT + (size_t)D_ * D_;          // [R][D]
    __hip_bfloat16* WuT = WdT + (size_t)R_ * D_;          // [2D][R]
    __hip_bfloat16* WoT = WuT + (size_t)TWO_D_ * R_;      // [D][D]
    __hip_bfloat16* xdb = WoT + (size_t)D_ * D_;          // BT*R
    __hip_bfloat16* kvb = xdb + (size_t)BT_ * R_;         // BT*2D
    float* q    = (float*)(kvb + (size_t)BT_ * TWO_D_);   // BT*D fp32
    float* ctx  = q + (size_t)BT_ * D_;                   // 64*4096
    float* ksum = ctx + (size_t)B_ * H_ * DH_ * DH_;      // 64*64
    __hip_bfloat16* outb = xb;   // alias: xb dead after GEMM2

    hipMemsetAsync(ctx, 0,
        (size_t)(B_ * H_ * DH_ * DH_ + B_ * H_ * DH_) * sizeof(float), stream);

    // casts
    cast_bf16_kernel<<<(BT_ * D_) / (8 * 256), 256, 0, stream>>>(x, xb, BT_ * D_);
    transpose_cast<<<dim3(D_ / 32, D_ / 32), 256, 0, stream>>>(Wq, WqT, D_, D_);
    transpose_cast<<<dim3(R_ / 32, D_ / 32), 256, 0, stream>>>(Wd, WdT, D_, R_);
    transpose_cast<<<dim3(TWO_D_ / 32, R_ / 32), 256, 0, stream>>>(Wu, WuT, R_, TWO_D_);
    transpose_cast<<<dim3(D_ / 32, D_ / 32), 256, 0, stream>>>(Wo, WoT, D_, D_);

    // 1) q = elu1(x @ Wq + bq)  (fp32 out, feeds normalizer)
    gemm_bf16<1, float><<<dim3(D_ / BN, BT_ / BM), 256, 0, stream>>>(
        xb, WqT, bq, q, BT_, D_, D_);
    // 2) xd = x @ Wd + bd  (bf16 out)
    gemm_bf16<0, __hip_bfloat16><<<dim3(R_ / BN, BT_ / BM), 256, 0, stream>>>(
        xb, WdT, bd, xdb, BT_, R_, D_);
    // 3) kv = xd @ Wu + bu, elu1 on k-part  (bf16 out)
    gemm_bf16<2, __hip_bfloat16><<<dim3(TWO_D_ / BN, BT_ / BM), 256, 0, stream>>>(
        xdb, WuT, bu, kvb, BT_, TWO_D_, R_);
    // 4) context + ksum
    ctx_kernel<<<B_ * H_ * (T_ / TCHUNK), 256, 0, stream>>>(kvb, ctx, ksum);
    // 5) out = z * (q @ ctx)  (bf16 out)
    out_kernel<<<B_ * H_ * (T_ / 64), 256, 0, stream>>>(q, ctx, ksum, outb);
    // 6) final = outb @ Wo + bo
    gemm_bf16<0, float><<<dim3(D_ / BN, BT_ / BM), 256, 0, stream>>>(
        outb, WoT, bo, out, BT_, D_, D_);
}

// Round 3
// 380.706 us; speedup vs baseline: 4.0027x; 1.4480x over previous
//
#include <hip/hip_runtime.h>
#include <hip/hip_bf16.h>
#include <cstddef>
#include <cstdint>

// Problem constants
#define B_  4
#define T_  4096
#define D_  1024
#define H_  16
#define DH_ 64
#define R_  256
#define BT_ (B_ * T_)       // 16384
#define TWO_D_ (2 * D_)     // 2048

typedef __attribute__((ext_vector_type(8))) short short8;
typedef __attribute__((ext_vector_type(4))) float f32x4;

__device__ __forceinline__ float elu1(float x) {
    return x > 0.0f ? x + 1.0f : __expf(x);
}

__device__ __forceinline__ float bf2f(short u) {
    union { uint32_t i; float f; } c;
    c.i = ((uint32_t)(uint16_t)u) << 16;
    return c.f;
}

typedef __attribute__((address_space(1))) void void_g;
typedef __attribute__((address_space(3))) void void_l;
__device__ __forceinline__ void gld_lds16(const void* g, void* l) {
    __builtin_amdgcn_global_load_lds(
        (const void_g*)(uintptr_t)g,
        (void_l*)(uint32_t)(uintptr_t)l,
        16, 0, 0);
}

// ---------------------------------------------------------------------------
// bf16 MFMA GEMM (m97 structure): C[M,N] = A[M,K] @ Bt[N,K]^T + bias.
// EPI 0: none; 1: elu1 all; 2: elu1 on k-part.
// BROW: bias indexed by row (for transposed-output GEMM3'), EPI2 tests row.
// ---------------------------------------------------------------------------
#define BM 128
#define BN 128
#define BK 32

__device__ __forceinline__ void store_out(float* p, float v) { *p = v; }
__device__ __forceinline__ void store_out(__hip_bfloat16* p, float v) { *p = __float2bfloat16(v); }

template<int EPI, bool BROW, typename OT>
__global__ __launch_bounds__(256) void gemm_bf16(
    const __hip_bfloat16* __restrict__ A,
    const __hip_bfloat16* __restrict__ Bt,
    const float* __restrict__ bias,
    OT* __restrict__ C,
    int M, int N, int K)
{
    __shared__ alignas(16) __hip_bfloat16 As[BM * BK];
    __shared__ alignas(16) __hip_bfloat16 Bs[BN * BK];

    const int tid  = threadIdx.x;
    const int lane = tid & 63;
    const int wm   = (tid >> 7) * 64;
    const int wn   = ((tid >> 6) & 1) * 64;
    const int bm   = blockIdx.y * BM;
    const int bn   = blockIdx.x * BN;
    const int r15  = lane & 15;
    const int kg   = lane >> 4;

    f32x4 acc[4][4] = {};

    const int c0 = tid, c1 = tid + 256;
    const __hip_bfloat16* a0 = A  + (size_t)(bm + (c0 >> 2)) * K + (c0 & 3) * 8;
    const __hip_bfloat16* a1 = A  + (size_t)(bm + (c1 >> 2)) * K + (c1 & 3) * 8;
    const __hip_bfloat16* b0 = Bt + (size_t)(bn + (c0 >> 2)) * K + (c0 & 3) * 8;
    const __hip_bfloat16* b1 = Bt + (size_t)(bn + (c1 >> 2)) * K + (c1 & 3) * 8;

    for (int k0 = 0; k0 < K; k0 += BK) {
        gld_lds16(a0 + k0, As + c0 * 8);
        gld_lds16(a1 + k0, As + c1 * 8);
        gld_lds16(b0 + k0, Bs + c0 * 8);
        gld_lds16(b1 + k0, Bs + c1 * 8);
        __syncthreads();

        short8 af[4], bf[4];
#pragma unroll
        for (int i = 0; i < 4; ++i) {
            af[i] = *(const short8*)(As + (wm + i * 16 + r15) * BK + kg * 8);
            bf[i] = *(const short8*)(Bs + (wn + i * 16 + r15) * BK + kg * 8);
        }
#pragma unroll
        for (int i = 0; i < 4; ++i)
#pragma unroll
            for (int j = 0; j < 4; ++j)
                acc[i][j] = __builtin_amdgcn_mfma_f32_16x16x32_bf16(af[i], bf[j], acc[i][j], 0, 0, 0);
        __syncthreads();
    }

    // C/D layout: col=lane&15, row=(lane>>4)*4+reg  [m89-verified]
    const int row0 = bm + wm + (lane >> 4) * 4;
    float brow[4][4];
    if (BROW) {
#pragma unroll
        for (int i = 0; i < 4; ++i)
#pragma unroll
            for (int r = 0; r < 4; ++r) brow[i][r] = bias[row0 + i * 16 + r];
    }
#pragma unroll
    for (int j = 0; j < 4; ++j) {
        const int col = bn + wn + j * 16 + r15;
        const float bv = BROW ? 0.0f : bias[col];
        const bool kp_col = ((col & 127) < 64);
#pragma unroll
        for (int i = 0; i < 4; ++i) {
#pragma unroll
            for (int r = 0; r < 4; ++r) {
                const int row = row0 + i * 16 + r;
                float v = acc[i][j][r] + (BROW ? brow[i][r] : bv);
                if (EPI == 1) v = elu1(v);
                else if (EPI == 2) {
                    const bool kp = BROW ? ((row & 127) < 64) : kp_col;
                    if (kp) v = elu1(v);
                }
                store_out(C + (size_t)row * N + col, v);
            }
        }
    }
}

// ---------------------------------------------------------------------------
__global__ __launch_bounds__(256) void cast_bf16_kernel(
    const float* __restrict__ s, __hip_bfloat16* __restrict__ d, int n)
{
    const int i = (blockIdx.x * 256 + threadIdx.x) * 8;
    if (i >= n) return;
    float4 v0 = *(const float4*)(s + i);
    float4 v1 = *(const float4*)(s + i + 4);
    __hip_bfloat16 t[8];
    t[0] = __float2bfloat16(v0.x); t[1] = __float2bfloat16(v0.y);
    t[2] = __float2bfloat16(v0.z); t[3] = __float2bfloat16(v0.w);
    t[4] = __float2bfloat16(v1.x); t[5] = __float2bfloat16(v1.y);
    t[6] = __float2bfloat16(v1.z); t[7] = __float2bfloat16(v1.w);
    *(short8*)(d + i) = *(const short8*)t;
}

__global__ __launch_bounds__(256) void transpose_cast(
    const float* __restrict__ W, __hip_bfloat16* __restrict__ Wt, int K, int N)
{
    __shared__ float t[32][33];
    const int n0 = blockIdx.x * 32, k0 = blockIdx.y * 32;
    const int c = threadIdx.x & 31, r = threadIdx.x >> 5;
#pragma unroll
    for (int rr = r; rr < 32; rr += 8)
        t[rr][c] = W[(size_t)(k0 + rr) * N + n0 + c];
    __syncthreads();
#pragma unroll
    for (int rr = r; rr < 32; rr += 8)
        Wt[(size_t)(n0 + rr) * K + k0 + c] = __float2bfloat16(t[c][rr]);
}

// ---------------------------------------------------------------------------
// ctx_mfma: ctx[bh][d][e] = sum_t K^T[d][t] * V^T[e][t]; ksum via ones-trick.
// kvT layout: [2048][BT_] bf16; rows h*128+0..63 = K^T, 64..127 = V^T.
// Grid: 64 bh x 8 chunks of 512 t. Block 256 thr = 4 waves, k-split by wave.
// ---------------------------------------------------------------------------
#define CHT 512

__global__ __launch_bounds__(256) void ctx_mfma(
    const __hip_bfloat16* __restrict__ kvT, float* __restrict__ ctx,
    float* __restrict__ ksum)
{
    // union: staging 32768 B (128 j x 128 t as [s][j][32]) / 2x 20480 B reduce
    __shared__ alignas(16) unsigned char smem[40960];
    float* red0 = (float*)smem;
    float* red1 = (float*)(smem + 20480);

    const int bh = blockIdx.x >> 3;
    const int chunk = blockIdx.x & 7;
    const int b = bh >> 4;
    const int h = bh & 15;
    const int tid = threadIdx.x;
    const int lane = tid & 63;
    const int w = tid >> 6;                 // wave id = t-slice
    const int r15 = lane & 15;
    const int kg  = lane >> 4;

    f32x4 acc[4][4] = {};
    f32x4 acc4[4] = {};                      // ones-tile -> ksum in col (64+r15)

    const short one = (short)0x3F80;         // bf16 1.0
    const short8 bfv = (r15 == 0)
        ? (short8){one, one, one, one, one, one, one, one}
        : (short8){0, 0, 0, 0, 0, 0, 0, 0};

    const size_t tbase = (size_t)b * T_ + (size_t)chunk * CHT;
    const __hip_bfloat16* src = kvT + (size_t)(h * 128) * BT_ + tbase;

    for (int it = 0; it < CHT / 128; ++it) {
        // stage [4 s][128 j][32 t] ; chunk c: s=c>>9, j=(c>>2)&127, u=c&3
#pragma unroll
        for (int r = 0; r < 8; ++r) {
            const int c = r * 256 + tid;
            const int s = c >> 9, j = (c >> 2) & 127, u = c & 3;
            gld_lds16(src + (size_t)j * BT_ + it * 128 + s * 32 + u * 8,
                      smem + c * 16);
        }
        __syncthreads();

        const __hip_bfloat16* Ls = (const __hip_bfloat16*)smem;
        short8 af[4], bf[4];
#pragma unroll
        for (int i = 0; i < 4; ++i) {
            af[i] = *(const short8*)(Ls + (w * 128 + i * 16 + r15) * 32 + kg * 8);
            bf[i] = *(const short8*)(Ls + (w * 128 + 64 + i * 16 + r15) * 32 + kg * 8);
        }
#pragma unroll
        for (int i = 0; i < 4; ++i) {
#pragma unroll
            for (int j = 0; j < 4; ++j)
                acc[i][j] = __builtin_amdgcn_mfma_f32_16x16x32_bf16(af[i], bf[j], acc[i][j], 0, 0, 0);
            acc4[i] = __builtin_amdgcn_mfma_f32_16x16x32_bf16(af[i], bfv, acc4[i], 0, 0, 0);
        }
        __syncthreads();
    }

    // tree-reduce 4 waves into red0 ([64 d][80 cols]: 0..63=e, 64=ksum)
    const int q4 = lane >> 4;
    auto wr = [&](float* reg) {
#pragma unroll
        for (int i = 0; i < 4; ++i) {
#pragma unroll
            for (int r = 0; r < 4; ++r) {
                const int row = i * 16 + q4 * 4 + r;
#pragma unroll
                for (int j = 0; j < 4; ++j) reg[row * 80 + j * 16 + r15] = acc[i][j][r];
                reg[row * 80 + 64 + r15] = acc4[i][r];
            }
        }
    };
    auto rd = [&](const float* reg) {
#pragma unroll
        for (int i = 0; i < 4; ++i) {
#pragma unroll
            for (int r = 0; r < 4; ++r) {
                const int row = i * 16 + q4 * 4 + r;
#pragma unroll
                for (int j = 0; j < 4; ++j) acc[i][j][r] += reg[row * 80 + j * 16 + r15];
                acc4[i][r] += reg[row * 80 + 64 + r15];
            }
        }
    };

    if (w == 1) wr(red0);
    if (w == 3) wr(red1);
    __syncthreads();
    if (w == 0) rd(red0);
    if (w == 2) rd(red1);
    __syncthreads();
    if (w == 2) wr(red0);
    __syncthreads();
    if (w == 0) { rd(red0); wr(red0); }
    __syncthreads();

    // atomic accumulate: 4096 ctx + 64 ksum
    float* cdst = ctx + (size_t)bh * 4096;
#pragma unroll
    for (int r = 0; r < 16; ++r) {
        const int idx = r * 256 + tid;
        const int d = idx >> 6, e = idx & 63;
        atomicAdd(cdst + idx, red0[d * 80 + e]);
    }
    if (tid < 64) atomicAdd(ksum + bh * 64 + tid, red0[tid * 80 + 64]);
}

// ---------------------------------------------------------------------------
// pack_ctx: ctxT[bh][e][d] = bf16(ctx[bh][d][e]). Grid 64, 256 thr.
// ---------------------------------------------------------------------------
__global__ __launch_bounds__(256) void pack_ctx(
    const float* __restrict__ ctx, __hip_bfloat16* __restrict__ ctxT)
{
    __shared__ float L[64 * 65];
    const int bh = blockIdx.x;
    const int tid = threadIdx.x;
#pragma unroll
    for (int r = 0; r < 16; ++r) {
        const int idx = r * 256 + tid;
        L[(idx >> 6) * 65 + (idx & 63)] = ctx[(size_t)bh * 4096 + idx];
    }
    __syncthreads();
#pragma unroll
    for (int r = 0; r < 16; ++r) {
        const int idx = r * 256 + tid;       // idx = e*64 + d
        ctxT[(size_t)bh * 4096 + idx] =
            __float2bfloat16(L[(idx & 63) * 65 + (idx >> 6)]);
    }
}

// ---------------------------------------------------------------------------
// out_mfma: out[t][h*64+e] = z_t * sum_d q[t][d] * ctx[d][e],
//           z_t = 1/(sum_d q[t][d]*ksum[d] + 1e-6), fp32 denominator.
// Grid: 64 bh x 16 tiles of 256 tokens. XOR-swizzled LDS (128 B rows).
// ---------------------------------------------------------------------------
__global__ __launch_bounds__(256) void out_mfma(
    const __hip_bfloat16* __restrict__ qb, const __hip_bfloat16* __restrict__ ctxT,
    const float* __restrict__ ksum, __hip_bfloat16* __restrict__ outb)
{
    __shared__ alignas(16) unsigned char As[256 * 128];   // 256 tok x 64 d bf16
    __shared__ alignas(16) unsigned char Bs[64 * 128];    // 64 e x 64 d bf16
    __shared__ float ksumL[64];
    __shared__ float zbuf[256];

    const int bh = blockIdx.x >> 4;
    const int tile = blockIdx.x & 15;
    const int b = bh >> 4;
    const int h = bh & 15;
    const int tid = threadIdx.x;
    const int lane = tid & 63;
    const int w = tid >> 6;
    const int r15 = lane & 15;
    const int kg  = lane >> 4;

    const size_t trow0 = (size_t)b * T_ + (size_t)tile * 256;

    // stage q tile: chunk c -> row c>>3, slot c&7, global u = slot ^ (row&7)
#pragma unroll
    for (int r = 0; r < 8; ++r) {
        const int c = r * 256 + tid;
        const int row = c >> 3, slot = c & 7, u = slot ^ (row & 7);
        gld_lds16(qb + (trow0 + row) * D_ + h * 64 + u * 8, As + c * 16);
    }
    // stage ctxT (64 rows x 64)
#pragma unroll
    for (int r = 0; r < 2; ++r) {
        const int c = r * 256 + tid;
        const int row = c >> 3, slot = c & 7, u = slot ^ (row & 7);
        gld_lds16(ctxT + (size_t)bh * 4096 + row * 64 + u * 8, Bs + c * 16);
    }
    if (tid < 64) ksumL[tid] = ksum[bh * 64 + tid];
    __syncthreads();

    // fragments: 2 k-steps (K=64)
    short8 af[4][2], bf[4][2];
#pragma unroll
    for (int i = 0; i < 4; ++i)
#pragma unroll
        for (int s = 0; s < 2; ++s) {
            const int m = w * 64 + i * 16 + r15;
            const int n = i * 16 + r15;
            const int uk = s * 4 + kg;
            af[i][s] = *(const short8*)(As + m * 128 + ((uk ^ (m & 7)) * 16));
            bf[i][s] = *(const short8*)(Bs + n * 128 + ((uk ^ (n & 7)) * 16));
        }

    f32x4 acc[4][4] = {};
#pragma unroll
    for (int s = 0; s < 2; ++s)
#pragma unroll
        for (int i = 0; i < 4; ++i)
#pragma unroll
            for (int j = 0; j < 4; ++j)
                acc[i][j] = __builtin_amdgcn_mfma_f32_16x16x32_bf16(af[i][s], bf[j][s], acc[i][j], 0, 0, 0);

    // fp32 denominator from A-fragments already in registers
    float dsum[4];
#pragma unroll
    for (int i = 0; i < 4; ++i) {
        float s0 = 0.0f;
#pragma unroll
        for (int s = 0; s < 2; ++s)
#pragma unroll
            for (int j8 = 0; j8 < 8; ++j8)
                s0 += bf2f(af[i][s][j8]) * ksumL[s * 32 + kg * 8 + j8];
        s0 += __shfl_xor(s0, 16);
        s0 += __shfl_xor(s0, 32);
        dsum[i] = s0;
    }
    if (lane < 16) {
#pragma unroll
        for (int i = 0; i < 4; ++i)
            zbuf[w * 64 + i * 16 + lane] = 1.0f / (dsum[i] + 1e-6f);
    }
    __syncthreads();

    // epilogue: scale by z, store bf16
    const int q4 = lane >> 4;
#pragma unroll
    for (int i = 0; i < 4; ++i) {
#pragma unroll
        for (int r = 0; r < 4; ++r) {
            const int m = w * 64 + i * 16 + q4 * 4 + r;
            const float z = zbuf[m];
#pragma unroll
            for (int j = 0; j < 4; ++j) {
                outb[(trow0 + m) * D_ + h * 64 + j * 16 + r15] =
                    __float2bfloat16(acc[i][j][r] * z);
            }
        }
    }
}

// ---------------------------------------------------------------------------
extern "C" void kernel_launch(void* const* d_in, const int* in_sizes, int n_in,
                              void* d_out, int out_size, void* d_ws, size_t ws_size,
                              hipStream_t stream) {
    const float* x  = (const float*)d_in[0];
    const float* Wq = (const float*)d_in[1];
    const float* bq = (const float*)d_in[2];
    const float* Wd = (const float*)d_in[3];
    const float* bd = (const float*)d_in[4];
    const float* Wu = (const float*)d_in[5];
    const float* bu = (const float*)d_in[6];
    const float* Wo = (const float*)d_in[7];
    const float* bo = (const float*)d_in[8];
    float* out = (float*)d_out;

    __hip_bfloat16* xb   = (__hip_bfloat16*)d_ws;           // BT*D
    __hip_bfloat16* WqT  = xb   + (size_t)BT_ * D_;
    __hip_bfloat16* WdT  = WqT  + (size_t)D_ * D_;
    __hip_bfloat16* WuT  = WdT  + (size_t)R_ * D_;
    __hip_bfloat16* WoT  = WuT  + (size_t)TWO_D_ * R_;
    __hip_bfloat16* xdb  = WoT  + (size_t)D_ * D_;          // BT*R
    __hip_bfloat16* kvT  = xdb  + (size_t)BT_ * R_;         // 2048*BT
    __hip_bfloat16* qb   = kvT  + (size_t)TWO_D_ * BT_;     // BT*D
    float* ctx  = (float*)(qb + (size_t)BT_ * D_);          // 64*4096
    float* ksum = ctx + (size_t)B_ * H_ * DH_ * DH_;        // 64*64
    __hip_bfloat16* ctxT = (__hip_bfloat16*)(ksum + B_ * H_ * DH_);  // 64*4096
    __hip_bfloat16* outb = xb;   // alias: xb dead after GEMM2

    hipMemsetAsync(ctx, 0,
        (size_t)(B_ * H_ * DH_ * DH_ + B_ * H_ * DH_) * sizeof(float), stream);

    cast_bf16_kernel<<<(BT_ * D_) / (8 * 256), 256, 0, stream>>>(x, xb, BT_ * D_);
    transpose_cast<<<dim3(D_ / 32, D_ / 32), 256, 0, stream>>>(Wq, WqT, D_, D_);
    transpose_cast<<<dim3(R_ / 32, D_ / 32), 256, 0, stream>>>(Wd, WdT, D_, R_);
    transpose_cast<<<dim3(TWO_D_ / 32, R_ / 32), 256, 0, stream>>>(Wu, WuT, R_, TWO_D_);
    transpose_cast<<<dim3(D_ / 32, D_ / 32), 256, 0, stream>>>(Wo, WoT, D_, D_);

    // 1) qb = bf16(elu1(x @ Wq + bq))
    gemm_bf16<1, false, __hip_bfloat16><<<dim3(D_ / BN, BT_ / BM), 256, 0, stream>>>(
        xb, WqT, bq, qb, BT_, D_, D_);
    // 2) xd = x @ Wd + bd
    gemm_bf16<0, false, __hip_bfloat16><<<dim3(R_ / BN, BT_ / BM), 256, 0, stream>>>(
        xb, WdT, bd, xdb, BT_, R_, D_);
    // 3) kvT[j][t] = Wu^T @ xd^T + bu[j], elu1 on rows (j&127)<64
    gemm_bf16<2, true, __hip_bfloat16><<<dim3(BT_ / BN, TWO_D_ / BM), 256, 0, stream>>>(
        WuT, xdb, bu, kvT, TWO_D_, BT_, R_);
    // 4) ctx + ksum via MFMA
    ctx_mfma<<<64 * (T_ / CHT), 256, 0, stream>>>(kvT, ctx, ksum);
    // 5) pack ctx -> bf16 transposed
    pack_ctx<<<64, 256, 0, stream>>>(ctx, ctxT);
    // 6) out = z * (q @ ctx)
    out_mfma<<<64 * 16, 256, 0, stream>>>(qb, ctxT, ksum, outb);
    // 7) final = outb @ Wo + bo
    gemm_bf16<0, false, float><<<dim3(D_ / BN, BT_ / BM), 256, 0, stream>>>(
        outb, WoT, bo, out, BT_, D_, D_);
}

// Round 4
// 353.984 us; speedup vs baseline: 4.3049x; 1.0755x over previous
//
#include <hip/hip_runtime.h>
#include <hip/hip_bf16.h>
#include <cstddef>
#include <cstdint>

// Problem constants
#define B_  4
#define T_  4096
#define D_  1024
#define H_  16
#define DH_ 64
#define R_  256
#define BT_ (B_ * T_)       // 16384
#define TWO_D_ (2 * D_)     // 2048

typedef __attribute__((ext_vector_type(8))) short short8;
typedef __attribute__((ext_vector_type(4))) float f32x4;

__device__ __forceinline__ float elu1(float x) {
    return x > 0.0f ? x + 1.0f : __expf(x);
}

__device__ __forceinline__ float bf2f(short u) {
    union { uint32_t i; float f; } c;
    c.i = ((uint32_t)(uint16_t)u) << 16;
    return c.f;
}

typedef __attribute__((address_space(1))) void void_g;
typedef __attribute__((address_space(3))) void void_l;
__device__ __forceinline__ void gld_lds16(const void* g, void* l) {
    __builtin_amdgcn_global_load_lds(
        (const void_g*)(uintptr_t)g,
        (void_l*)(uint32_t)(uintptr_t)l,
        16, 0, 0);
}

// ---------------------------------------------------------------------------
// bf16 MFMA GEMM (m97 structure): C[M,N] = A[M,K] @ Bt[N,K]^T + bias.
// 1-D grid with 8-row-strip col-major swizzle for XCD L2 locality:
// 64 consecutive block ids touch <=8 A-tiles + <=8 B-tiles (~4 MB).
// EPI 0: none; 1: elu1 all; 2: elu1 on k-part; 3: split q/xd store.
// BROW: bias indexed by row (transposed-output GEMM3'), EPI2 tests row.
// ---------------------------------------------------------------------------
#define BM 128
#define BN 128
#define BK 32

__device__ __forceinline__ void store_out(float* p, float v) { *p = v; }
__device__ __forceinline__ void store_out(__hip_bfloat16* p, float v) { *p = __float2bfloat16(v); }

template<int EPI, bool BROW, typename OT>
__global__ __launch_bounds__(256) void gemm_bf16(
    const __hip_bfloat16* __restrict__ A,
    const __hip_bfloat16* __restrict__ Bt,
    const float* __restrict__ bias,
    OT* __restrict__ C,
    OT* __restrict__ C2,
    int M, int N, int K)
{
    __shared__ alignas(16) __hip_bfloat16 As[BM * BK];
    __shared__ alignas(16) __hip_bfloat16 Bs[BN * BK];

    // swizzle: strips of 8 row-tiles, col-major within strip (M/BM % 8 == 0)
    const int nbx = N / BN;
    const int id = blockIdx.x;
    const int strip = id / (8 * nbx);
    const int wi = id % (8 * nbx);
    const int bm = (strip * 8 + (wi & 7)) * BM;
    const int bn = (wi >> 3) * BN;

    const int tid  = threadIdx.x;
    const int lane = tid & 63;
    const int wm   = (tid >> 7) * 64;
    const int wn   = ((tid >> 6) & 1) * 64;
    const int r15  = lane & 15;
    const int kg   = lane >> 4;

    f32x4 acc[4][4] = {};

    const int c0 = tid, c1 = tid + 256;
    const __hip_bfloat16* a0 = A  + (size_t)(bm + (c0 >> 2)) * K + (c0 & 3) * 8;
    const __hip_bfloat16* a1 = A  + (size_t)(bm + (c1 >> 2)) * K + (c1 & 3) * 8;
    const __hip_bfloat16* b0 = Bt + (size_t)(bn + (c0 >> 2)) * K + (c0 & 3) * 8;
    const __hip_bfloat16* b1 = Bt + (size_t)(bn + (c1 >> 2)) * K + (c1 & 3) * 8;

    for (int k0 = 0; k0 < K; k0 += BK) {
        gld_lds16(a0 + k0, As + c0 * 8);
        gld_lds16(a1 + k0, As + c1 * 8);
        gld_lds16(b0 + k0, Bs + c0 * 8);
        gld_lds16(b1 + k0, Bs + c1 * 8);
        __syncthreads();

        short8 af[4], bf[4];
#pragma unroll
        for (int i = 0; i < 4; ++i) {
            af[i] = *(const short8*)(As + (wm + i * 16 + r15) * BK + kg * 8);
            bf[i] = *(const short8*)(Bs + (wn + i * 16 + r15) * BK + kg * 8);
        }
#pragma unroll
        for (int i = 0; i < 4; ++i)
#pragma unroll
            for (int j = 0; j < 4; ++j)
                acc[i][j] = __builtin_amdgcn_mfma_f32_16x16x32_bf16(af[i], bf[j], acc[i][j], 0, 0, 0);
        __syncthreads();
    }

    // C/D layout: col=lane&15, row=(lane>>4)*4+reg  [m89-verified]
    const int row0 = bm + wm + (lane >> 4) * 4;

    if (EPI == 3) {
        // cols < 1024: q = elu1(.) at stride 1024; cols >= 1024: xd at stride 256
        const bool qreg = (bn < 1024);
#pragma unroll
        for (int j = 0; j < 4; ++j) {
            const int col = bn + wn + j * 16 + r15;
            const float bv = bias[col];
#pragma unroll
            for (int i = 0; i < 4; ++i)
#pragma unroll
                for (int r = 0; r < 4; ++r) {
                    const int row = row0 + i * 16 + r;
                    float v = acc[i][j][r] + bv;
                    if (qreg) {
                        store_out(C + (size_t)row * 1024 + col, elu1(v));
                    } else {
                        store_out(C2 + (size_t)row * 256 + (col - 1024), v);
                    }
                }
        }
        return;
    }

    float brow[4][4];
    if (BROW) {
#pragma unroll
        for (int i = 0; i < 4; ++i)
#pragma unroll
            for (int r = 0; r < 4; ++r) brow[i][r] = bias[row0 + i * 16 + r];
    }
#pragma unroll
    for (int j = 0; j < 4; ++j) {
        const int col = bn + wn + j * 16 + r15;
        const float bv = BROW ? 0.0f : bias[col];
        const bool kp_col = ((col & 127) < 64);
#pragma unroll
        for (int i = 0; i < 4; ++i) {
#pragma unroll
            for (int r = 0; r < 4; ++r) {
                const int row = row0 + i * 16 + r;
                float v = acc[i][j][r] + (BROW ? brow[i][r] : bv);
                if (EPI == 1) v = elu1(v);
                else if (EPI == 2) {
                    const bool kp = BROW ? ((row & 127) < 64) : kp_col;
                    if (kp) v = elu1(v);
                }
                store_out(C + (size_t)row * N + col, v);
            }
        }
    }
}

// ---------------------------------------------------------------------------
__global__ __launch_bounds__(256) void cast_bf16_kernel(
    const float* __restrict__ s, __hip_bfloat16* __restrict__ d, int n)
{
    const int i = (blockIdx.x * 256 + threadIdx.x) * 8;
    if (i >= n) return;
    float4 v0 = *(const float4*)(s + i);
    float4 v1 = *(const float4*)(s + i + 4);
    __hip_bfloat16 t[8];
    t[0] = __float2bfloat16(v0.x); t[1] = __float2bfloat16(v0.y);
    t[2] = __float2bfloat16(v0.z); t[3] = __float2bfloat16(v0.w);
    t[4] = __float2bfloat16(v1.x); t[5] = __float2bfloat16(v1.y);
    t[6] = __float2bfloat16(v1.z); t[7] = __float2bfloat16(v1.w);
    *(short8*)(d + i) = *(const short8*)t;
}

__global__ __launch_bounds__(256) void transpose_cast(
    const float* __restrict__ W, __hip_bfloat16* __restrict__ Wt, int K, int N)
{
    __shared__ float t[32][33];
    const int n0 = blockIdx.x * 32, k0 = blockIdx.y * 32;
    const int c = threadIdx.x & 31, r = threadIdx.x >> 5;
#pragma unroll
    for (int rr = r; rr < 32; rr += 8)
        t[rr][c] = W[(size_t)(k0 + rr) * N + n0 + c];
    __syncthreads();
#pragma unroll
    for (int rr = r; rr < 32; rr += 8)
        Wt[(size_t)(n0 + rr) * K + k0 + c] = __float2bfloat16(t[c][rr]);
}

__global__ __launch_bounds__(256) void concat_bias(
    const float* __restrict__ bq, const float* __restrict__ bd,
    float* __restrict__ o)
{
    const int i = blockIdx.x * 256 + threadIdx.x;   // 0..1279
    o[i] = (i < 1024) ? bq[i] : bd[i - 1024];
}

// ---------------------------------------------------------------------------
// ctx_mfma: ctx[bh][d][e] = sum_t K^T[d][t] * V^T[e][t]; ksum via ones-trick.
// kvT layout: [2048][BT_] bf16; rows h*128+0..63 = K^T, 64..127 = V^T.
// ---------------------------------------------------------------------------
#define CHT 512

__global__ __launch_bounds__(256) void ctx_mfma(
    const __hip_bfloat16* __restrict__ kvT, float* __restrict__ ctx,
    float* __restrict__ ksum)
{
    __shared__ alignas(16) unsigned char smem[40960];
    float* red0 = (float*)smem;
    float* red1 = (float*)(smem + 20480);

    const int bh = blockIdx.x >> 3;
    const int chunk = blockIdx.x & 7;
    const int b = bh >> 4;
    const int h = bh & 15;
    const int tid = threadIdx.x;
    const int lane = tid & 63;
    const int w = tid >> 6;
    const int r15 = lane & 15;
    const int kg  = lane >> 4;

    f32x4 acc[4][4] = {};
    f32x4 acc4[4] = {};

    const short one = (short)0x3F80;
    const short8 bfv = (r15 == 0)
        ? (short8){one, one, one, one, one, one, one, one}
        : (short8){0, 0, 0, 0, 0, 0, 0, 0};

    const size_t tbase = (size_t)b * T_ + (size_t)chunk * CHT;
    const __hip_bfloat16* src = kvT + (size_t)(h * 128) * BT_ + tbase;

    for (int it = 0; it < CHT / 128; ++it) {
#pragma unroll
        for (int r = 0; r < 8; ++r) {
            const int c = r * 256 + tid;
            const int s = c >> 9, j = (c >> 2) & 127, u = c & 3;
            gld_lds16(src + (size_t)j * BT_ + it * 128 + s * 32 + u * 8,
                      smem + c * 16);
        }
        __syncthreads();

        const __hip_bfloat16* Ls = (const __hip_bfloat16*)smem;
        short8 af[4], bf[4];
#pragma unroll
        for (int i = 0; i < 4; ++i) {
            af[i] = *(const short8*)(Ls + (w * 128 + i * 16 + r15) * 32 + kg * 8);
            bf[i] = *(const short8*)(Ls + (w * 128 + 64 + i * 16 + r15) * 32 + kg * 8);
        }
#pragma unroll
        for (int i = 0; i < 4; ++i) {
#pragma unroll
            for (int j = 0; j < 4; ++j)
                acc[i][j] = __builtin_amdgcn_mfma_f32_16x16x32_bf16(af[i], bf[j], acc[i][j], 0, 0, 0);
            acc4[i] = __builtin_amdgcn_mfma_f32_16x16x32_bf16(af[i], bfv, acc4[i], 0, 0, 0);
        }
        __syncthreads();
    }

    const int q4 = lane >> 4;
    auto wr = [&](float* reg) {
#pragma unroll
        for (int i = 0; i < 4; ++i) {
#pragma unroll
            for (int r = 0; r < 4; ++r) {
                const int row = i * 16 + q4 * 4 + r;
#pragma unroll
                for (int j = 0; j < 4; ++j) reg[row * 80 + j * 16 + r15] = acc[i][j][r];
                reg[row * 80 + 64 + r15] = acc4[i][r];
            }
        }
    };
    auto rd = [&](const float* reg) {
#pragma unroll
        for (int i = 0; i < 4; ++i) {
#pragma unroll
            for (int r = 0; r < 4; ++r) {
                const int row = i * 16 + q4 * 4 + r;
#pragma unroll
                for (int j = 0; j < 4; ++j) acc[i][j][r] += reg[row * 80 + j * 16 + r15];
                acc4[i][r] += reg[row * 80 + 64 + r15];
            }
        }
    };

    if (w == 1) wr(red0);
    if (w == 3) wr(red1);
    __syncthreads();
    if (w == 0) rd(red0);
    if (w == 2) rd(red1);
    __syncthreads();
    if (w == 2) wr(red0);
    __syncthreads();
    if (w == 0) { rd(red0); wr(red0); }
    __syncthreads();

    float* cdst = ctx + (size_t)bh * 4096;
#pragma unroll
    for (int r = 0; r < 16; ++r) {
        const int idx = r * 256 + tid;
        const int d = idx >> 6, e = idx & 63;
        atomicAdd(cdst + idx, red0[d * 80 + e]);
    }
    if (tid < 64) atomicAdd(ksum + bh * 64 + tid, red0[tid * 80 + 64]);
}

// ---------------------------------------------------------------------------
__global__ __launch_bounds__(256) void pack_ctx(
    const float* __restrict__ ctx, __hip_bfloat16* __restrict__ ctxT)
{
    __shared__ float L[64 * 65];
    const int bh = blockIdx.x;
    const int tid = threadIdx.x;
#pragma unroll
    for (int r = 0; r < 16; ++r) {
        const int idx = r * 256 + tid;
        L[(idx >> 6) * 65 + (idx & 63)] = ctx[(size_t)bh * 4096 + idx];
    }
    __syncthreads();
#pragma unroll
    for (int r = 0; r < 16; ++r) {
        const int idx = r * 256 + tid;
        ctxT[(size_t)bh * 4096 + idx] =
            __float2bfloat16(L[(idx & 63) * 65 + (idx >> 6)]);
    }
}

// ---------------------------------------------------------------------------
// out_mfma: out[t][h*64+e] = z_t * sum_d q[t][d] * ctx[d][e]
// ---------------------------------------------------------------------------
__global__ __launch_bounds__(256) void out_mfma(
    const __hip_bfloat16* __restrict__ qb, const __hip_bfloat16* __restrict__ ctxT,
    const float* __restrict__ ksum, __hip_bfloat16* __restrict__ outb)
{
    __shared__ alignas(16) unsigned char As[256 * 128];
    __shared__ alignas(16) unsigned char Bs[64 * 128];
    __shared__ float ksumL[64];
    __shared__ float zbuf[256];

    const int bh = blockIdx.x >> 4;
    const int tile = blockIdx.x & 15;
    const int b = bh >> 4;
    const int h = bh & 15;
    const int tid = threadIdx.x;
    const int lane = tid & 63;
    const int w = tid >> 6;
    const int r15 = lane & 15;
    const int kg  = lane >> 4;

    const size_t trow0 = (size_t)b * T_ + (size_t)tile * 256;

#pragma unroll
    for (int r = 0; r < 8; ++r) {
        const int c = r * 256 + tid;
        const int row = c >> 3, slot = c & 7, u = slot ^ (row & 7);
        gld_lds16(qb + (trow0 + row) * D_ + h * 64 + u * 8, As + c * 16);
    }
#pragma unroll
    for (int r = 0; r < 2; ++r) {
        const int c = r * 256 + tid;
        const int row = c >> 3, slot = c & 7, u = slot ^ (row & 7);
        gld_lds16(ctxT + (size_t)bh * 4096 + row * 64 + u * 8, Bs + c * 16);
    }
    if (tid < 64) ksumL[tid] = ksum[bh * 64 + tid];
    __syncthreads();

    short8 af[4][2], bf[4][2];
#pragma unroll
    for (int i = 0; i < 4; ++i)
#pragma unroll
        for (int s = 0; s < 2; ++s) {
            const int m = w * 64 + i * 16 + r15;
            const int n = i * 16 + r15;
            const int uk = s * 4 + kg;
            af[i][s] = *(const short8*)(As + m * 128 + ((uk ^ (m & 7)) * 16));
            bf[i][s] = *(const short8*)(Bs + n * 128 + ((uk ^ (n & 7)) * 16));
        }

    f32x4 acc[4][4] = {};
#pragma unroll
    for (int s = 0; s < 2; ++s)
#pragma unroll
        for (int i = 0; i < 4; ++i)
#pragma unroll
            for (int j = 0; j < 4; ++j)
                acc[i][j] = __builtin_amdgcn_mfma_f32_16x16x32_bf16(af[i][s], bf[j][s], acc[i][j], 0, 0, 0);

    float dsum[4];
#pragma unroll
    for (int i = 0; i < 4; ++i) {
        float s0 = 0.0f;
#pragma unroll
        for (int s = 0; s < 2; ++s)
#pragma unroll
            for (int j8 = 0; j8 < 8; ++j8)
                s0 += bf2f(af[i][s][j8]) * ksumL[s * 32 + kg * 8 + j8];
        s0 += __shfl_xor(s0, 16);
        s0 += __shfl_xor(s0, 32);
        dsum[i] = s0;
    }
    if (lane < 16) {
#pragma unroll
        for (int i = 0; i < 4; ++i)
            zbuf[w * 64 + i * 16 + lane] = 1.0f / (dsum[i] + 1e-6f);
    }
    __syncthreads();

    const int q4 = lane >> 4;
#pragma unroll
    for (int i = 0; i < 4; ++i) {
#pragma unroll
        for (int r = 0; r < 4; ++r) {
            const int m = w * 64 + i * 16 + q4 * 4 + r;
            const float z = zbuf[m];
#pragma unroll
            for (int j = 0; j < 4; ++j) {
                outb[(trow0 + m) * D_ + h * 64 + j * 16 + r15] =
                    __float2bfloat16(acc[i][j][r] * z);
            }
        }
    }
}

// ---------------------------------------------------------------------------
extern "C" void kernel_launch(void* const* d_in, const int* in_sizes, int n_in,
                              void* d_out, int out_size, void* d_ws, size_t ws_size,
                              hipStream_t stream) {
    const float* x  = (const float*)d_in[0];
    const float* Wq = (const float*)d_in[1];
    const float* bq = (const float*)d_in[2];
    const float* Wd = (const float*)d_in[3];
    const float* bd = (const float*)d_in[4];
    const float* Wu = (const float*)d_in[5];
    const float* bu = (const float*)d_in[6];
    const float* Wo = (const float*)d_in[7];
    const float* bo = (const float*)d_in[8];
    float* out = (float*)d_out;

    __hip_bfloat16* xb    = (__hip_bfloat16*)d_ws;            // BT*D
    __hip_bfloat16* WqdT  = xb    + (size_t)BT_ * D_;         // [1280][1024]
    __hip_bfloat16* WuT   = WqdT  + (size_t)1280 * D_;        // [2048][256]
    __hip_bfloat16* WoT   = WuT   + (size_t)TWO_D_ * R_;      // [1024][1024]
    __hip_bfloat16* xdb   = WoT   + (size_t)D_ * D_;          // BT*R
    __hip_bfloat16* kvT   = xdb   + (size_t)BT_ * R_;         // 2048*BT
    __hip_bfloat16* qb    = kvT   + (size_t)TWO_D_ * BT_;     // BT*D
    float* bias_qd = (float*)(qb + (size_t)BT_ * D_);         // 1280
    float* ctx  = bias_qd + 1280;                             // 64*4096
    float* ksum = ctx + (size_t)B_ * H_ * DH_ * DH_;          // 64*64
    __hip_bfloat16* ctxT = (__hip_bfloat16*)(ksum + B_ * H_ * DH_);  // 64*4096
    __hip_bfloat16* outb = xb;   // alias: xb dead after fused GEMM12

    hipMemsetAsync(ctx, 0,
        (size_t)(B_ * H_ * DH_ * DH_ + B_ * H_ * DH_) * sizeof(float), stream);

    cast_bf16_kernel<<<(BT_ * D_) / (8 * 256), 256, 0, stream>>>(x, xb, BT_ * D_);
    transpose_cast<<<dim3(D_ / 32, D_ / 32), 256, 0, stream>>>(Wq, WqdT, D_, D_);
    transpose_cast<<<dim3(R_ / 32, D_ / 32), 256, 0, stream>>>(Wd, WqdT + (size_t)D_ * D_, D_, R_);
    transpose_cast<<<dim3(TWO_D_ / 32, R_ / 32), 256, 0, stream>>>(Wu, WuT, R_, TWO_D_);
    transpose_cast<<<dim3(D_ / 32, D_ / 32), 256, 0, stream>>>(Wo, WoT, D_, D_);
    concat_bias<<<5, 256, 0, stream>>>(bq, bd, bias_qd);

    // 1+2) fused: [q | xd] = x @ [Wq|Wd] + [bq|bd]; elu1 + split store
    gemm_bf16<3, false, __hip_bfloat16><<<(BT_ / BM) * (1280 / BN), 256, 0, stream>>>(
        xb, WqdT, bias_qd, qb, xdb, BT_, 1280, D_);
    // 3) kvT[j][t] = Wu^T @ xd^T + bu[j], elu1 on rows (j&127)<64
    gemm_bf16<2, true, __hip_bfloat16><<<(TWO_D_ / BM) * (BT_ / BN), 256, 0, stream>>>(
        WuT, xdb, bu, kvT, nullptr, TWO_D_, BT_, R_);
    // 4) ctx + ksum via MFMA
    ctx_mfma<<<64 * (T_ / CHT), 256, 0, stream>>>(kvT, ctx, ksum);
    // 5) pack ctx -> bf16 transposed
    pack_ctx<<<64, 256, 0, stream>>>(ctx, ctxT);
    // 6) out = z * (q @ ctx)
    out_mfma<<<64 * 16, 256, 0, stream>>>(qb, ctxT, ksum, outb);
    // 7) final = outb @ Wo + bo
    gemm_bf16<0, false, float><<<(BT_ / BM) * (D_ / BN), 256, 0, stream>>>(
        outb, WoT, bo, out, nullptr, BT_, D_, D_);
}